// Round 1
// baseline (1698.117 us; speedup 1.0000x reference)
//
#include <hip/hip_runtime.h>
#include <hip/hip_bf16.h>

#define E_ 16
#define H_ 2048
#define I_ 1408
#define BM 128
#define BN 128
#define BK 32
#define SB 48   // LDS row stride in bf16 elems (96 B, 16B-aligned rows)

typedef __attribute__((ext_vector_type(8))) short bf16x8;
typedef __attribute__((ext_vector_type(4))) float f32x4;

// Swizzled LDS offset: row-major [row][k], stride SB, with the four 16B
// k-chunks rotated by (row>>2)&3 to break the 96B-row bank pattern.
// Frag reads land 2-way conflicted (free per m136); staging writes ~8-way.
__device__ __forceinline__ int swz(int row, int e) {
  return row * SB + ((((e >> 3) + (row >> 2)) & 3) << 3) + (e & 7);
}

__device__ __forceinline__ unsigned int pk2(float a, float b) {
  __hip_bfloat162 h = __float22bfloat162_rn(make_float2(a, b));
  unsigned int u;
  __builtin_memcpy(&u, &h, 4);
  return u;  // low 16 = a, high 16 = b
}

__device__ __forceinline__ unsigned short bf16b(float a) {
  unsigned int u = __builtin_bit_cast(unsigned int, a);
  u = (u + 0x7fffu + ((u >> 16) & 1u)) >> 16;  // RNE
  return (unsigned short)u;
}

// ---------------- Router: logits (fp64) -> top-2 -> renorm weights ----------
__global__ __launch_bounds__(64) void moe_router(
    const float* __restrict__ x, const float* __restrict__ gw,
    int* __restrict__ counts, int* __restrict__ list2s,
    float* __restrict__ listw, int T)
{
  const int lane = threadIdx.x;
  const int t0 = blockIdx.x * 4;
  double acc[4][16];
#pragma unroll
  for (int i = 0; i < 4; ++i)
#pragma unroll
    for (int j = 0; j < 16; ++j) acc[i][j] = 0.0;

  const float4* gw4 = (const float4*)gw;
  for (int it = 0; it < H_ / 64; ++it) {
    const int h = it * 64 + lane;
    float gv[16];
    *(float4*)&gv[0]  = gw4[h * 4 + 0];
    *(float4*)&gv[4]  = gw4[h * 4 + 1];
    *(float4*)&gv[8]  = gw4[h * 4 + 2];
    *(float4*)&gv[12] = gw4[h * 4 + 3];
    float xr[4];
#pragma unroll
    for (int i = 0; i < 4; ++i) xr[i] = x[(size_t)(t0 + i) * H_ + h];
#pragma unroll
    for (int i = 0; i < 4; ++i) {
      const double xv = (double)xr[i];
#pragma unroll
      for (int j = 0; j < 16; ++j) acc[i][j] += xv * (double)gv[j];
    }
  }
  // full butterfly: every lane ends with the complete sums
#pragma unroll
  for (int i = 0; i < 4; ++i)
#pragma unroll
    for (int j = 0; j < 16; ++j) {
      double v = acc[i][j];
#pragma unroll
      for (int m = 32; m > 0; m >>= 1) v += __shfl_xor(v, m, 64);
      acc[i][j] = v;
    }
  if (lane == 0) {
#pragma unroll
    for (int i = 0; i < 4; ++i) {
      const int t = t0 + i;
      double b1 = -1e300, b2 = -1e300;
      int i1 = 0, i2 = 0;
#pragma unroll
      for (int j = 0; j < 16; ++j) {
        const double l = acc[i][j];
        if (l > b1) { b2 = b1; i2 = i1; b1 = l; i1 = j; }
        else if (l > b2) { b2 = l; i2 = j; }
      }
      // softmax denom cancels under top-2 renorm: w = 1/(1+e^{l2-l1})
      const float ex = expf((float)(b2 - b1));
      const float wa = 1.f / (1.f + ex);
      const float wb = ex / (1.f + ex);
      int p = atomicAdd(&counts[i1], 1);
      list2s[i1 * T + p] = t * 2;
      listw[i1 * T + p] = wa;
      p = atomicAdd(&counts[i2], 1);
      list2s[i2 * T + p] = t * 2 + 1;
      listw[i2 * T + p] = wb;
    }
  }
}

// Transpose-convert a 4k x 4n fp32 weight patch into [n][k] bf16 LDS tile.
__device__ __forceinline__ void stage_b(const float* __restrict__ bp,
                                        unsigned short* Bs, int bn, int bk, int ldb) {
  const float4 r0 = *(const float4*)(bp);
  const float4 r1 = *(const float4*)(bp + ldb);
  const float4 r2 = *(const float4*)(bp + 2 * ldb);
  const float4 r3 = *(const float4*)(bp + 3 * ldb);
  uint2 c;
  c.x = pk2(r0.x, r1.x); c.y = pk2(r2.x, r3.x);
  *(uint2*)&Bs[swz(bn + 0, bk)] = c;
  c.x = pk2(r0.y, r1.y); c.y = pk2(r2.y, r3.y);
  *(uint2*)&Bs[swz(bn + 1, bk)] = c;
  c.x = pk2(r0.z, r1.z); c.y = pk2(r2.z, r3.z);
  *(uint2*)&Bs[swz(bn + 2, bk)] = c;
  c.x = pk2(r0.w, r1.w); c.y = pk2(r2.w, r3.w);
  *(uint2*)&Bs[swz(bn + 3, bk)] = c;
}

// ---------------- GEMM1: act = silu(Xe@W1e) * (Xe@W3e), gathered rows -------
__global__ __launch_bounds__(256) void moe_gemm1(
    const float* __restrict__ x, const float* __restrict__ w1,
    const float* __restrict__ w3, const int* __restrict__ counts,
    const int* __restrict__ list2s, unsigned short* __restrict__ act, int T)
{
  const int e = blockIdx.z;
  const int cnt = counts[e];
  const int m0 = blockIdx.y * BM;
  if (m0 >= cnt) return;
  const int n0 = blockIdx.x * BN;
  const float* w1e = w1 + (size_t)e * H_ * I_;
  const float* w3e = w3 + (size_t)e * H_ * I_;
  const int* lst = list2s + (size_t)e * T;

  __shared__ unsigned short As[BM * SB], B1s[BN * SB], B3s[BN * SB];

  const int tid = threadIdx.x;
  const int lane = tid & 63, wave = tid >> 6;
  const int wr = (wave >> 1) * 64, wc = (wave & 1) * 64;
  const int l16 = lane & 15, quad = lane >> 4;

  // A staging: 2 threads per row, 16 fp32 each
  const int ar = tid >> 1, ahalf = tid & 1;
  const int apos = m0 + ar;
  const int a_t2s = lst[apos < cnt ? apos : cnt - 1];
  const float* aptr = x + (size_t)(a_t2s >> 1) * H_ + ahalf * 16;

  // B staging: thread covers 4k x 4n patch (n-fast thread order -> coalesced)
  const int nq = tid & 31, kb = tid >> 5;
  const int bn = nq * 4, bk = kb * 4;

  f32x4 acc1[4][4], acc3[4][4];
  const f32x4 fz = {0.f, 0.f, 0.f, 0.f};
#pragma unroll
  for (int mi = 0; mi < 4; ++mi)
#pragma unroll
    for (int ni = 0; ni < 4; ++ni) { acc1[mi][ni] = fz; acc3[mi][ni] = fz; }

  for (int k0 = 0; k0 < H_; k0 += BK) {
    __syncthreads();
    {
      const float4 a0 = *(const float4*)(aptr + k0);
      const float4 a1 = *(const float4*)(aptr + k0 + 4);
      const float4 a2 = *(const float4*)(aptr + k0 + 8);
      const float4 a3 = *(const float4*)(aptr + k0 + 12);
      uint4 A0, A1;
      A0.x = pk2(a0.x, a0.y); A0.y = pk2(a0.z, a0.w);
      A0.z = pk2(a1.x, a1.y); A0.w = pk2(a1.z, a1.w);
      A1.x = pk2(a2.x, a2.y); A1.y = pk2(a2.z, a2.w);
      A1.z = pk2(a3.x, a3.y); A1.w = pk2(a3.z, a3.w);
      *(uint4*)&As[swz(ar, ahalf * 16)] = A0;
      *(uint4*)&As[swz(ar, ahalf * 16 + 8)] = A1;
    }
    stage_b(w1e + (size_t)(k0 + bk) * I_ + n0 + bn, B1s, bn, bk, I_);
    stage_b(w3e + (size_t)(k0 + bk) * I_ + n0 + bn, B3s, bn, bk, I_);
    __syncthreads();

    bf16x8 af[4], b1f[4], b3f[4];
#pragma unroll
    for (int mi = 0; mi < 4; ++mi)
      af[mi] = *(const bf16x8*)&As[swz(wr + mi * 16 + l16, quad * 8)];
#pragma unroll
    for (int ni = 0; ni < 4; ++ni) {
      b1f[ni] = *(const bf16x8*)&B1s[swz(wc + ni * 16 + l16, quad * 8)];
      b3f[ni] = *(const bf16x8*)&B3s[swz(wc + ni * 16 + l16, quad * 8)];
    }
#pragma unroll
    for (int mi = 0; mi < 4; ++mi)
#pragma unroll
      for (int ni = 0; ni < 4; ++ni) {
        acc1[mi][ni] = __builtin_amdgcn_mfma_f32_16x16x32_bf16(af[mi], b1f[ni], acc1[mi][ni], 0, 0, 0);
        acc3[mi][ni] = __builtin_amdgcn_mfma_f32_16x16x32_bf16(af[mi], b3f[ni], acc3[mi][ni], 0, 0, 0);
      }
  }

  // epilogue: silu(g)*u -> bf16 act[token*2+slot][I]
#pragma unroll
  for (int mi = 0; mi < 4; ++mi) {
    const int rbase = m0 + wr + mi * 16 + quad * 4;
#pragma unroll
    for (int r = 0; r < 4; ++r) {
      const int pos = rbase + r;
      if (pos < cnt) {
        const int t2s = lst[pos];
        unsigned short* op = act + (size_t)t2s * I_ + n0 + wc + l16;
#pragma unroll
        for (int ni = 0; ni < 4; ++ni) {
          const float g = acc1[mi][ni][r];
          const float u = acc3[mi][ni][r];
          const float s = g / (1.f + __expf(-g));
          op[ni * 16] = bf16b(s * u);
        }
      }
    }
  }
}

// ---------------- GEMM2: out[t] += w * (act @ W2e) ---------------------------
__global__ __launch_bounds__(256) void moe_gemm2(
    const unsigned short* __restrict__ act, const float* __restrict__ w2,
    const int* __restrict__ counts, const int* __restrict__ list2s,
    const float* __restrict__ listw, float* __restrict__ out, int T)
{
  const int e = blockIdx.z;
  const int cnt = counts[e];
  const int m0 = blockIdx.y * BM;
  if (m0 >= cnt) return;
  const int n0 = blockIdx.x * BN;
  const float* w2e = w2 + (size_t)e * I_ * H_;
  const int* lst = list2s + (size_t)e * T;
  const float* lw = listw + (size_t)e * T;

  __shared__ unsigned short As[BM * SB], Bs[BN * SB];

  const int tid = threadIdx.x;
  const int lane = tid & 63, wave = tid >> 6;
  const int wr = (wave >> 1) * 64, wc = (wave & 1) * 64;
  const int l16 = lane & 15, quad = lane >> 4;

  const int ar = tid >> 1, ahalf = tid & 1;
  const int apos = m0 + ar;
  const int a_t2s = lst[apos < cnt ? apos : cnt - 1];
  const unsigned short* aptr = act + (size_t)a_t2s * I_ + ahalf * 16;

  const int nq = tid & 31, kb = tid >> 5;
  const int bn = nq * 4, bk = kb * 4;

  f32x4 acc[4][4];
  const f32x4 fz = {0.f, 0.f, 0.f, 0.f};
#pragma unroll
  for (int mi = 0; mi < 4; ++mi)
#pragma unroll
    for (int ni = 0; ni < 4; ++ni) acc[mi][ni] = fz;

  for (int k0 = 0; k0 < I_; k0 += BK) {
    __syncthreads();
    {
      const uint4 A0 = *(const uint4*)(aptr + k0);      // 8 bf16
      const uint4 A1 = *(const uint4*)(aptr + k0 + 8);  // 8 bf16
      *(uint4*)&As[swz(ar, ahalf * 16)] = A0;
      *(uint4*)&As[swz(ar, ahalf * 16 + 8)] = A1;
    }
    stage_b(w2e + (size_t)(k0 + bk) * H_ + n0 + bn, Bs, bn, bk, H_);
    __syncthreads();

    bf16x8 af[4], bf[4];
#pragma unroll
    for (int mi = 0; mi < 4; ++mi)
      af[mi] = *(const bf16x8*)&As[swz(wr + mi * 16 + l16, quad * 8)];
#pragma unroll
    for (int ni = 0; ni < 4; ++ni)
      bf[ni] = *(const bf16x8*)&Bs[swz(wc + ni * 16 + l16, quad * 8)];
#pragma unroll
    for (int mi = 0; mi < 4; ++mi)
#pragma unroll
      for (int ni = 0; ni < 4; ++ni)
        acc[mi][ni] = __builtin_amdgcn_mfma_f32_16x16x32_bf16(af[mi], bf[ni], acc[mi][ni], 0, 0, 0);
  }

  // epilogue: scaled scatter-add (each out element hit exactly TOP_K=2 times)
#pragma unroll
  for (int mi = 0; mi < 4; ++mi) {
    const int rbase = m0 + wr + mi * 16 + quad * 4;
#pragma unroll
    for (int r = 0; r < 4; ++r) {
      const int pos = rbase + r;
      if (pos < cnt) {
        const int t2s = lst[pos];
        const float wt = lw[pos];
        float* op = out + (size_t)(t2s >> 1) * H_ + n0 + wc + l16;
#pragma unroll
        for (int ni = 0; ni < 4; ++ni)
          atomicAdd(op + ni * 16, wt * acc[mi][ni][r]);
      }
    }
  }
}

extern "C" void kernel_launch(void* const* d_in, const int* in_sizes, int n_in,
                              void* d_out, int out_size, void* d_ws, size_t ws_size,
                              hipStream_t stream) {
  const float* x  = (const float*)d_in[0];
  const float* gw = (const float*)d_in[1];
  const float* w1 = (const float*)d_in[2];
  const float* w3 = (const float*)d_in[3];
  const float* w2 = (const float*)d_in[4];
  float* out = (float*)d_out;
  const int T = in_sizes[0] / H_;  // 8192

  // workspace layout (ws re-poisoned every call -> re-init counts each call)
  char* ws = (char*)d_ws;
  int* counts = (int*)ws;                                        // 64 B (pad 256)
  int* list2s = (int*)(ws + 256);                                // E*T*4
  float* listw = (float*)(ws + 256 + (size_t)E_ * T * 4);        // E*T*4
  unsigned short* act = (unsigned short*)(ws + 256 + 2 * (size_t)E_ * T * 4);  // 2T*I*2 B

  hipMemsetAsync(counts, 0, 256, stream);
  hipMemsetAsync(out, 0, (size_t)out_size * sizeof(float), stream);
  moe_router<<<T / 4, 64, 0, stream>>>(x, gw, counts, list2s, listw, T);
  moe_gemm1<<<dim3(I_ / BN, T / BM, E_), 256, 0, stream>>>(x, w1, w3, counts, list2s, act, T);
  moe_gemm2<<<dim3(H_ / BN, T / BM, E_), 256, 0, stream>>>(act, w2, counts, list2s, listw, out, T);
}